// Round 2
// baseline (154.897 us; speedup 1.0000x reference)
//
#include <hip/hip_runtime.h>

constexpr int NSAMP = 32768;
constexpr int DIM   = 2048;
constexpr int NCLS  = 512;
constexpr double EPS = 1e-6;
constexpr int CHUNK = 16;       // rows per main-kernel block
constexpr int NCHUNK = 16;      // max chunks/class -> supports count <= 256 (24 sigma)

// ws layout (byte offsets):
//   0        : float S[512][2048]   (4 MB)  -- per-class column sums (atomic f32)
//   4<<20    : double acc[2]        {Q = sum x^2, T3 = sum_c |S_c|^2/cnt_c}
//   +64      : int counts[512]
//   +64+2048 : int offsets[512]
//   +8192    : int idx_list[32768]

__global__ void __launch_bounds__(1024) k_prep(const int* __restrict__ label,
                                               int* __restrict__ counts,
                                               int* __restrict__ offsets,
                                               int* __restrict__ idx_list) {
    __shared__ int h[NCLS];    // histogram
    __shared__ int sc[NCLS];   // scan / cursors
    const int t = threadIdx.x;
    if (t < NCLS) h[t] = 0;
    __syncthreads();
    for (int i = t; i < NSAMP; i += 1024) atomicAdd(&h[label[i]], 1);
    __syncthreads();
    if (t < NCLS) sc[t] = h[t];
    __syncthreads();
    // Hillis-Steele inclusive scan over 512 entries
    for (int off = 1; off < NCLS; off <<= 1) {
        int v = 0;
        if (t < NCLS && t >= off) v = sc[t - off];
        __syncthreads();
        if (t < NCLS) sc[t] += v;
        __syncthreads();
    }
    if (t < NCLS) {
        const int excl = sc[t] - h[t];
        counts[t]  = h[t];
        offsets[t] = excl;
        sc[t] = excl;          // becomes the fill cursor (global position)
    }
    __syncthreads();
    for (int i = t; i < NSAMP; i += 1024) {
        const int c = label[i];
        const int p = atomicAdd(&sc[c], 1);
        idx_list[p] = i;
    }
}

// grid = (2 col-slices * NCHUNK, NCLS), block = 256.
// blockIdx.x: bit0 = column slice (0/1), bits[4:1] = row chunk.
// Each thread owns 4 contiguous columns (float4) within a 1024-col slice.
__global__ void __launch_bounds__(256) k_main(const float* __restrict__ x,
                                              const int* __restrict__ counts,
                                              const int* __restrict__ offsets,
                                              const int* __restrict__ idx_list,
                                              float* __restrict__ S,
                                              double* __restrict__ acc) {
    const int c     = blockIdx.y;
    const int slice = blockIdx.x & 1;
    const int chunk = blockIdx.x >> 1;
    const int cnt   = counts[c];
    const int r0    = chunk * CHUNK;
    if (r0 >= cnt) return;
    const int r1 = (chunk == NCHUNK - 1) ? cnt : min(cnt, r0 + CHUNK);
    const int base = offsets[c];

    const float* xp = x + slice * 1024 + threadIdx.x * 4;

    float Sx = 0.f, Sy = 0.f, Sz = 0.f, Sw = 0.f;
    float Q  = 0.f;

    int r = r0;
    for (; r + 4 <= r1; r += 4) {
        const int i0 = idx_list[base + r + 0];
        const int i1 = idx_list[base + r + 1];
        const int i2 = idx_list[base + r + 2];
        const int i3 = idx_list[base + r + 3];
        const float4 a = *reinterpret_cast<const float4*>(xp + (size_t)i0 * DIM);
        const float4 b = *reinterpret_cast<const float4*>(xp + (size_t)i1 * DIM);
        const float4 e = *reinterpret_cast<const float4*>(xp + (size_t)i2 * DIM);
        const float4 f = *reinterpret_cast<const float4*>(xp + (size_t)i3 * DIM);
        Sx += a.x + b.x + e.x + f.x;
        Sy += a.y + b.y + e.y + f.y;
        Sz += a.z + b.z + e.z + f.z;
        Sw += a.w + b.w + e.w + f.w;
        Q += a.x*a.x + a.y*a.y + a.z*a.z + a.w*a.w;
        Q += b.x*b.x + b.y*b.y + b.z*b.z + b.w*b.w;
        Q += e.x*e.x + e.y*e.y + e.z*e.z + e.w*e.w;
        Q += f.x*f.x + f.y*f.y + f.z*f.z + f.w*f.w;
    }
    for (; r < r1; ++r) {
        const int i0 = idx_list[base + r];
        const float4 a = *reinterpret_cast<const float4*>(xp + (size_t)i0 * DIM);
        Sx += a.x; Sy += a.y; Sz += a.z; Sw += a.w;
        Q += a.x*a.x + a.y*a.y + a.z*a.z + a.w*a.w;
    }

    // combine partial column sums into the global per-class sum (f32 atomics)
    float* Sp = S + (size_t)c * DIM + slice * 1024 + threadIdx.x * 4;
    atomicAdd(Sp + 0, Sx);
    atomicAdd(Sp + 1, Sy);
    atomicAdd(Sp + 2, Sz);
    atomicAdd(Sp + 3, Sw);

    // block-reduce Q -> one double atomic
    __shared__ double sq[256];
    sq[threadIdx.x] = (double)Q;
    __syncthreads();
    for (int o = 128; o > 0; o >>= 1) {
        if (threadIdx.x < o) sq[threadIdx.x] += sq[threadIdx.x + o];
        __syncthreads();
    }
    if (threadIdx.x == 0) atomicAdd(&acc[0], sq[0]);
}

// grid = NCLS blocks x 256 threads: T3 contribution of each class.
__global__ void __launch_bounds__(256) k_post(const float* __restrict__ S,
                                              const int* __restrict__ counts,
                                              double* __restrict__ acc) {
    const int c = blockIdx.x;
    const int cnt = counts[c];
    const float* Sp = S + (size_t)c * DIM;
    double p = 0.0;
    for (int j = threadIdx.x; j < DIM; j += 256) {
        const double v = (double)Sp[j];
        p += v * v;
    }
    __shared__ double sd[256];
    sd[threadIdx.x] = p;
    __syncthreads();
    for (int o = 128; o > 0; o >>= 1) {
        if (threadIdx.x < o) sd[threadIdx.x] += sd[threadIdx.x + o];
        __syncthreads();
    }
    if (threadIdx.x == 0 && cnt > 0) atomicAdd(&acc[1], sd[0] / (double)cnt);
}

__global__ void k_final(const double* __restrict__ acc, float* __restrict__ out) {
    // loss = (Q - T3)/N + D*eps^2   (the 2*eps linear term cancels exactly)
    out[0] = (float)((acc[0] - acc[1]) / (double)NSAMP + (double)DIM * EPS * EPS);
}

extern "C" void kernel_launch(void* const* d_in, const int* in_sizes, int n_in,
                              void* d_out, int out_size, void* d_ws, size_t ws_size,
                              hipStream_t stream) {
    const float* x     = (const float*)d_in[0];
    const int*   label = (const int*)d_in[1];
    float*       out   = (float*)d_out;

    char* ws = (char*)d_ws;
    float*  S        = (float*)(ws + 0);
    double* acc      = (double*)(ws + (4u << 20));
    int*    counts   = (int*)(ws + (4u << 20) + 64);
    int*    offsets  = (int*)(ws + (4u << 20) + 64 + 2048);
    int*    idx_list = (int*)(ws + (4u << 20) + 8192);

    // zero S (4 MB) + acc (16 B) in one async memset (capture-safe)
    hipMemsetAsync(ws, 0, (4u << 20) + 16, stream);

    hipLaunchKernelGGL(k_prep, dim3(1), dim3(1024), 0, stream,
                       label, counts, offsets, idx_list);
    hipLaunchKernelGGL(k_main, dim3(2 * NCHUNK, NCLS), dim3(256), 0, stream,
                       x, counts, offsets, idx_list, S, acc);
    hipLaunchKernelGGL(k_post, dim3(NCLS), dim3(256), 0, stream, S, counts, acc);
    hipLaunchKernelGGL(k_final, dim3(1), dim3(1), 0, stream, acc, out);
}

// Round 3
// 87.120 us; speedup vs baseline: 1.7780x; 1.7780x over previous
//
#include <hip/hip_runtime.h>

constexpr int NSAMP = 32768;
constexpr int DIM   = 2048;
constexpr int NCLS  = 512;
constexpr double EPS = 1e-6;
constexpr int NSLICE = 8;            // 8 slices x 256 cols = 2048
constexpr int NPART  = NSLICE * NCLS;  // 4096 partial slots

// ws layout (byte offsets):
//   0      : int counts[512]
//   2048   : int offsets[512]
//   4096   : int idx_list[32768]      (131072 B)
//   135168 : double partQ[4096]       (32768 B)
//   167936 : double partT[4096]       (32768 B)

__global__ void __launch_bounds__(1024) k_prep(const int* __restrict__ label,
                                               int* __restrict__ counts,
                                               int* __restrict__ offsets,
                                               int* __restrict__ idx_list) {
    __shared__ int h[NCLS];
    __shared__ int sc[NCLS];
    const int t = threadIdx.x;
    if (t < NCLS) h[t] = 0;
    __syncthreads();
    for (int i = t; i < NSAMP; i += 1024) atomicAdd(&h[label[i]], 1);
    __syncthreads();
    if (t < NCLS) sc[t] = h[t];
    __syncthreads();
    for (int off = 1; off < NCLS; off <<= 1) {
        int v = 0;
        if (t < NCLS && t >= off) v = sc[t - off];
        __syncthreads();
        if (t < NCLS) sc[t] += v;
        __syncthreads();
    }
    if (t < NCLS) {
        const int excl = sc[t] - h[t];
        counts[t]  = h[t];
        offsets[t] = excl;
        sc[t] = excl;                 // fill cursor
    }
    __syncthreads();
    for (int i = t; i < NSAMP; i += 1024) {
        const int c = label[i];
        const int p = atomicAdd(&sc[c], 1);
        idx_list[p] = i;
    }
}

// grid = (NSLICE, NCLS), block = 64 (one wave). Thread owns 4 contiguous cols
// (float4) in a 256-col slice; block accumulates its whole class in registers.
// Zero global atomics; per-block partials to private slots.
__global__ void __launch_bounds__(64) k_main(const float* __restrict__ x,
                                             const int* __restrict__ counts,
                                             const int* __restrict__ offsets,
                                             const int* __restrict__ idx_list,
                                             double* __restrict__ partQ,
                                             double* __restrict__ partT) {
    const int c    = blockIdx.y;
    const int s    = blockIdx.x;
    const int cnt  = counts[c];
    const int base = offsets[c];
    const float* xp = x + s * 256 + threadIdx.x * 4;

    float Sx = 0.f, Sy = 0.f, Sz = 0.f, Sw = 0.f;
    float Q  = 0.f;

    int r = 0;
    for (; r + 4 <= cnt; r += 4) {
        const int i0 = idx_list[base + r + 0];
        const int i1 = idx_list[base + r + 1];
        const int i2 = idx_list[base + r + 2];
        const int i3 = idx_list[base + r + 3];
        const float4 a = *reinterpret_cast<const float4*>(xp + (size_t)i0 * DIM);
        const float4 b = *reinterpret_cast<const float4*>(xp + (size_t)i1 * DIM);
        const float4 e = *reinterpret_cast<const float4*>(xp + (size_t)i2 * DIM);
        const float4 f = *reinterpret_cast<const float4*>(xp + (size_t)i3 * DIM);
        Sx += a.x + b.x + e.x + f.x;
        Sy += a.y + b.y + e.y + f.y;
        Sz += a.z + b.z + e.z + f.z;
        Sw += a.w + b.w + e.w + f.w;
        Q += a.x*a.x + a.y*a.y + a.z*a.z + a.w*a.w;
        Q += b.x*b.x + b.y*b.y + b.z*b.z + b.w*b.w;
        Q += e.x*e.x + e.y*e.y + e.z*e.z + e.w*e.w;
        Q += f.x*f.x + f.y*f.y + f.z*f.z + f.w*f.w;
    }
    for (; r < cnt; ++r) {
        const int i0 = idx_list[base + r];
        const float4 a = *reinterpret_cast<const float4*>(xp + (size_t)i0 * DIM);
        Sx += a.x; Sy += a.y; Sz += a.z; Sw += a.w;
        Q += a.x*a.x + a.y*a.y + a.z*a.z + a.w*a.w;
    }

    // per-thread contribution to |S_c|^2 over its 4 cols, in f64
    double s2 = (double)Sx*(double)Sx + (double)Sy*(double)Sy
              + (double)Sz*(double)Sz + (double)Sw*(double)Sw;
    double q  = (double)Q;

    // wave (64-lane) shuffle reduction — no LDS, no syncs
    #pragma unroll
    for (int off = 32; off > 0; off >>= 1) {
        q  += __shfl_down(q,  off, 64);
        s2 += __shfl_down(s2, off, 64);
    }
    if (threadIdx.x == 0) {
        const int slot = c * NSLICE + s;
        partQ[slot] = q;
        partT[slot] = (cnt > 0) ? (s2 / (double)cnt) : 0.0;
    }
}

__global__ void __launch_bounds__(256) k_final(const double* __restrict__ partQ,
                                               const double* __restrict__ partT,
                                               float* __restrict__ out) {
    double q = 0.0, t3 = 0.0;
    for (int i = threadIdx.x; i < NPART; i += 256) {
        q  += partQ[i];
        t3 += partT[i];
    }
    __shared__ double sq[256], st[256];
    sq[threadIdx.x] = q;
    st[threadIdx.x] = t3;
    __syncthreads();
    for (int o = 128; o > 0; o >>= 1) {
        if (threadIdx.x < o) {
            sq[threadIdx.x] += sq[threadIdx.x + o];
            st[threadIdx.x] += st[threadIdx.x + o];
        }
        __syncthreads();
    }
    if (threadIdx.x == 0) {
        // loss = (Q - T3)/N + D*eps^2  (the 2*eps linear term cancels exactly)
        out[0] = (float)((sq[0] - st[0]) / (double)NSAMP + (double)DIM * EPS * EPS);
    }
}

extern "C" void kernel_launch(void* const* d_in, const int* in_sizes, int n_in,
                              void* d_out, int out_size, void* d_ws, size_t ws_size,
                              hipStream_t stream) {
    const float* x     = (const float*)d_in[0];
    const int*   label = (const int*)d_in[1];
    float*       out   = (float*)d_out;

    char* ws = (char*)d_ws;
    int*    counts   = (int*)(ws + 0);
    int*    offsets  = (int*)(ws + 2048);
    int*    idx_list = (int*)(ws + 4096);
    double* partQ    = (double*)(ws + 135168);
    double* partT    = (double*)(ws + 167936);

    hipLaunchKernelGGL(k_prep, dim3(1), dim3(1024), 0, stream,
                       label, counts, offsets, idx_list);
    hipLaunchKernelGGL(k_main, dim3(NSLICE, NCLS), dim3(64), 0, stream,
                       x, counts, offsets, idx_list, partQ, partT);
    hipLaunchKernelGGL(k_final, dim3(1), dim3(256), 0, stream, partQ, partT, out);
}

// Round 4
// 82.174 us; speedup vs baseline: 1.8850x; 1.0602x over previous
//
#include <hip/hip_runtime.h>

constexpr int NSAMP = 32768;
constexpr int DIM   = 2048;
constexpr int NCLS  = 512;
constexpr double EPS = 1e-6;
constexpr int NSLICE = 8;              // 8 slices x 256 cols = 2048
constexpr int NPART  = NSLICE * NCLS;  // 4096 partial slots

// ws layout (byte offsets):
//   0      : int counts[512]          (2048 B)
//   2048   : int cursors[512]         (2048 B)
//   4096   : int offsets[512]         (2048 B)
//   8192   : int idx_list[32768]      (131072 B)
//   139264 : double partQ[4096]       (32768 B)
//   172032 : double partT[4096]       (32768 B)

__global__ void __launch_bounds__(256) k_hist(const int* __restrict__ label,
                                              int* __restrict__ counts) {
    const int i = blockIdx.x * 256 + threadIdx.x;
    if (i < NSAMP) atomicAdd(&counts[label[i]], 1);
}

__global__ void __launch_bounds__(512) k_scan(const int* __restrict__ counts,
                                              int* __restrict__ offsets,
                                              int* __restrict__ cursors) {
    __shared__ int s[NCLS];
    const int t = threadIdx.x;
    const int h = counts[t];
    s[t] = h;
    __syncthreads();
    for (int off = 1; off < NCLS; off <<= 1) {
        int v = (t >= off) ? s[t - off] : 0;
        __syncthreads();
        s[t] += v;
        __syncthreads();
    }
    const int excl = s[t] - h;
    offsets[t] = excl;
    cursors[t] = excl;   // absolute fill cursor
}

__global__ void __launch_bounds__(256) k_fill(const int* __restrict__ label,
                                              int* __restrict__ cursors,
                                              int* __restrict__ idx_list) {
    const int i = blockIdx.x * 256 + threadIdx.x;
    if (i < NSAMP) {
        const int c = label[i];
        const int p = atomicAdd(&cursors[c], 1);
        idx_list[p] = i;
    }
}

// grid = (NSLICE, NCLS), block = 64 (one wave). Thread owns 4 contiguous cols
// (float4) in a 256-col slice; block accumulates its whole class in registers.
// Zero global atomics; 8-row unroll for memory-level parallelism.
__global__ void __launch_bounds__(64) k_main(const float* __restrict__ x,
                                             const int* __restrict__ counts,
                                             const int* __restrict__ offsets,
                                             const int* __restrict__ idx_list,
                                             double* __restrict__ partQ,
                                             double* __restrict__ partT) {
    const int c    = blockIdx.y;
    const int s    = blockIdx.x;
    const int cnt  = counts[c];
    const int base = offsets[c];
    const float* xp = x + s * 256 + threadIdx.x * 4;

    float SxA = 0.f, SyA = 0.f, SzA = 0.f, SwA = 0.f;
    float SxB = 0.f, SyB = 0.f, SzB = 0.f, SwB = 0.f;
    float QA = 0.f, QB = 0.f;

    int r = 0;
    for (; r + 8 <= cnt; r += 8) {
        int idx[8];
        #pragma unroll
        for (int j = 0; j < 8; ++j) idx[j] = idx_list[base + r + j];
        float4 v[8];
        #pragma unroll
        for (int j = 0; j < 8; ++j)
            v[j] = *reinterpret_cast<const float4*>(xp + (size_t)idx[j] * DIM);
        #pragma unroll
        for (int j = 0; j < 8; j += 2) {
            SxA += v[j].x; SyA += v[j].y; SzA += v[j].z; SwA += v[j].w;
            QA += v[j].x*v[j].x + v[j].y*v[j].y + v[j].z*v[j].z + v[j].w*v[j].w;
            SxB += v[j+1].x; SyB += v[j+1].y; SzB += v[j+1].z; SwB += v[j+1].w;
            QB += v[j+1].x*v[j+1].x + v[j+1].y*v[j+1].y + v[j+1].z*v[j+1].z + v[j+1].w*v[j+1].w;
        }
    }
    for (; r < cnt; ++r) {
        const int i0 = idx_list[base + r];
        const float4 a = *reinterpret_cast<const float4*>(xp + (size_t)i0 * DIM);
        SxA += a.x; SyA += a.y; SzA += a.z; SwA += a.w;
        QA += a.x*a.x + a.y*a.y + a.z*a.z + a.w*a.w;
    }

    const float Sx = SxA + SxB, Sy = SyA + SyB, Sz = SzA + SzB, Sw = SwA + SwB;
    double s2 = (double)Sx*(double)Sx + (double)Sy*(double)Sy
              + (double)Sz*(double)Sz + (double)Sw*(double)Sw;
    double q  = (double)(QA + QB);

    // wave (64-lane) shuffle reduction — no LDS, no syncs
    #pragma unroll
    for (int off = 32; off > 0; off >>= 1) {
        q  += __shfl_down(q,  off, 64);
        s2 += __shfl_down(s2, off, 64);
    }
    if (threadIdx.x == 0) {
        const int slot = c * NSLICE + s;
        partQ[slot] = q;
        partT[slot] = (cnt > 0) ? (s2 / (double)cnt) : 0.0;
    }
}

__global__ void __launch_bounds__(256) k_final(const double* __restrict__ partQ,
                                               const double* __restrict__ partT,
                                               float* __restrict__ out) {
    double q = 0.0, t3 = 0.0;
    for (int i = threadIdx.x; i < NPART; i += 256) {
        q  += partQ[i];
        t3 += partT[i];
    }
    __shared__ double sq[256], st[256];
    sq[threadIdx.x] = q;
    st[threadIdx.x] = t3;
    __syncthreads();
    for (int o = 128; o > 0; o >>= 1) {
        if (threadIdx.x < o) {
            sq[threadIdx.x] += sq[threadIdx.x + o];
            st[threadIdx.x] += st[threadIdx.x + o];
        }
        __syncthreads();
    }
    if (threadIdx.x == 0) {
        // loss = (Q - T3)/N + D*eps^2  (the 2*eps linear term cancels exactly)
        out[0] = (float)((sq[0] - st[0]) / (double)NSAMP + (double)DIM * EPS * EPS);
    }
}

extern "C" void kernel_launch(void* const* d_in, const int* in_sizes, int n_in,
                              void* d_out, int out_size, void* d_ws, size_t ws_size,
                              hipStream_t stream) {
    const float* x     = (const float*)d_in[0];
    const int*   label = (const int*)d_in[1];
    float*       out   = (float*)d_out;

    char* ws = (char*)d_ws;
    int*    counts   = (int*)(ws + 0);
    int*    cursors  = (int*)(ws + 2048);
    int*    offsets  = (int*)(ws + 4096);
    int*    idx_list = (int*)(ws + 8192);
    double* partQ    = (double*)(ws + 139264);
    double* partT    = (double*)(ws + 172032);

    hipMemsetAsync(ws, 0, 4096, stream);   // zero counts + cursors
    hipLaunchKernelGGL(k_hist, dim3(NSAMP / 256), dim3(256), 0, stream, label, counts);
    hipLaunchKernelGGL(k_scan, dim3(1), dim3(NCLS), 0, stream, counts, offsets, cursors);
    hipLaunchKernelGGL(k_fill, dim3(NSAMP / 256), dim3(256), 0, stream, label, cursors, idx_list);
    hipLaunchKernelGGL(k_main, dim3(NSLICE, NCLS), dim3(64), 0, stream,
                       x, counts, offsets, idx_list, partQ, partT);
    hipLaunchKernelGGL(k_final, dim3(1), dim3(256), 0, stream, partQ, partT, out);
}